// Round 8
// baseline (213.045 us; speedup 1.0000x reference)
//
#include <hip/hip_runtime.h>
#include <stdint.h>

typedef short s16x8 __attribute__((ext_vector_type(8)));
typedef float f32x4 __attribute__((ext_vector_type(4)));
typedef unsigned short u16;
typedef unsigned int u32;

__device__ __forceinline__ float bf2f(u16 u) {
  union { u32 i; float f; } v; v.i = ((u32)u) << 16; return v.f;
}
__device__ __forceinline__ u16 f2bf(float f) {  // round-to-nearest-even
  union { float f; u32 i; } v; v.f = f;
  u32 i = v.i;
  return (u16)((i + 0x7fffu + ((i >> 16) & 1u)) >> 16);
}
__device__ __forceinline__ u16 f2bf_fast(float f) {  // round-half-up
  union { float f; u32 i; } v; v.f = f;
  return (u16)((v.i + 0x8000u) >> 16);
}

__device__ __forceinline__ s16x8 load8(const void* p, size_t idx, int isf32) {
  s16x8 r;
  if (isf32) {
    const float* f = (const float*)p + idx;
    f32x4 a = *(const f32x4*)f;
    f32x4 b = *(const f32x4*)(f + 4);
#pragma unroll
    for (int j = 0; j < 4; j++) {
      r[j] = (short)f2bf(a[j]);
      r[4 + j] = (short)f2bf(b[j]);
    }
  } else {
    r = *(const s16x8*)((const u16*)p + idx);
  }
  return r;
}
__device__ __forceinline__ float loadf(const void* p, size_t idx, int isf32) {
  return isf32 ? ((const float*)p)[idx] : bf2f(((const u16*)p)[idx]);
}

// async global->LDS 16B/lane; LDS dest = wave-uniform base + lane*16.
__device__ __forceinline__ void cp16(const u16* g, u16* l) {
  __builtin_amdgcn_global_load_lds(
      (const __attribute__((address_space(1))) u32*)g,
      (__attribute__((address_space(3))) u32*)l, 16, 0, 0);
}

// ---------------------------------------------------------------------------
// Dtype detector (R3-proven): flags[0]=1 if inputs fp32, flags[1]=0.
// ---------------------------------------------------------------------------
__global__ void detect_dtype(const u16* __restrict__ x, int* __restrict__ flags) {
  int cnt = 0;
  for (int i = threadIdx.x; i < 4096; i += 64) {
    int e = (x[i] >> 7) & 0xFF;
    if (e >= 0xF0) cnt++;
  }
  unsigned long long any = __ballot(cnt > 0);
  if (threadIdx.x == 0) {
    flags[0] = (any != 0ull) ? 1 : 0;
    flags[1] = 0;
  }
}

// ---------------------------------------------------------------------------
// convert_x -> TILED bf16 layout: xb_t[mB][kB][kq][r][8], tile = 128 rows x
// 32 k (8KB). Writes contiguous (tid*8).
// ---------------------------------------------------------------------------
__global__ __launch_bounds__(256) void convert_x(const void* __restrict__ x,
                                                 const int* __restrict__ fp,
                                                 u16* __restrict__ xb) {
  int tid = blockIdx.x * 256 + threadIdx.x;  // 0..524287
  int r = tid & 127, kq = (tid >> 7) & 3, kB = (tid >> 9) & 31, mB = tid >> 14;
  size_t src = (size_t)(mB * 128 + r) * 1024 + kB * 32 + kq * 8;
  *(s16x8*)(xb + (size_t)tid * 8) = load8(x, src, *fp);
}

// ---------------------------------------------------------------------------
// Fused weight transposes into TILED layouts:
//   WqkvT_t[nB(24)][kB(32)][kq(4)][r(128)][8]   (tile rows = 128, for NT=128)
//   WprojT_t[nB(16)][kB(32)][kq(4)][r(64)][8]   (tile rows = 64,  for NT=64)
// u32-packed conflict-free LDS transpose (R4-proven core); n-fast store order
// keeps 64-thread groups writing 1KB contiguous. grid (48+16, 16).
// ---------------------------------------------------------------------------
__global__ __launch_bounds__(256) void transposeW2(
    const void* __restrict__ Wqkv, const void* __restrict__ Wproj,
    const int* __restrict__ fp, u16* __restrict__ WqkvT,
    u16* __restrict__ WprojT) {
  __shared__ u32 tile32[32 * 66];
  const int f = *fp;
  const int tid = threadIdx.x;
  const int bx = blockIdx.x;
  const void* W;
  u16* WT;
  int N, nb, qkvSide;
  if (bx < 48) { W = Wqkv; WT = WqkvT; N = 3072; nb = bx * 64; qkvSide = 1; }
  else         { W = Wproj; WT = WprojT; N = 1024; nb = (bx - 48) * 64; qkvSide = 0; }
  const int kb = blockIdx.y * 64;  // K = 1024
  {
    int a = tid >> 3, c8 = tid & 7;
    s16x8 r0 = load8(W, (size_t)(kb + 2 * a) * N + nb + c8 * 8, f);
    s16x8 r1 = load8(W, (size_t)(kb + 2 * a + 1) * N + nb + c8 * 8, f);
#pragma unroll
    for (int j = 0; j < 8; j++)
      tile32[a * 66 + c8 * 8 + j] = (u32)(u16)r0[j] | ((u32)(u16)r1[j] << 16);
  }
  __syncthreads();
#pragma unroll
  for (int i = 0; i < 2; i++) {
    int idx = tid + i * 256;
    int n = idx & 63, c8 = idx >> 6;  // n fast -> contiguous tiled stores
    s16x8 v;
#pragma unroll
    for (int w = 0; w < 4; w++) {
      u32 pk = tile32[(c8 * 4 + w) * 66 + n];
      v[2 * w] = (short)(u16)(pk & 0xFFFF);
      v[2 * w + 1] = (short)(u16)(pk >> 16);
    }
    int R = nb + n, k = kb + c8 * 8;
    int kB = k >> 5, kq = (k >> 3) & 3;
    size_t off;
    if (qkvSide) {
      int nB = R >> 7, r = R & 127;
      off = ((size_t)(nB * 32 + kB) * 4 + kq) * 1024 + r * 8;
    } else {
      int nB = R >> 6, r = R & 63;
      off = (size_t)(nB * 32 + kB) * 2048 + kq * 512 + r * 8;
    }
    *(s16x8*)(WT + off) = v;
  }
}

// ---------------------------------------------------------------------------
// V transpose: qkv V cols -> vT[bh*64+d][2048] (R6-proven, conflict-free).
// ---------------------------------------------------------------------------
__global__ __launch_bounds__(256) void transposeV(const u16* __restrict__ qkv,
                                                  u16* __restrict__ vT) {
  __shared__ u32 tile32[64 * 33];
  const int tid = threadIdx.x;
  const int tb = blockIdx.x * 64, bh = blockIdx.y;
  const int b = bh >> 4, h = bh & 15;
  {
    int a = tid >> 3, c8 = tid & 7;
    const u16* base = qkv + (size_t)(b * 2048 + tb + 2 * a) * 3072 + 2048 + h * 64;
    s16x8 r0 = *(const s16x8*)(base + c8 * 8);
    s16x8 r1 = *(const s16x8*)(base + 3072 + c8 * 8);
#pragma unroll
    for (int j = 0; j < 8; j++)
      tile32[(c8 * 8 + j) * 33 + a] = (u32)(u16)r0[j] | ((u32)(u16)r1[j] << 16);
  }
  __syncthreads();
#pragma unroll
  for (int i = 0; i < 2; i++) {
    int idx = tid + i * 256;
    int d = idx >> 3, c8 = idx & 7;
    s16x8 v;
#pragma unroll
    for (int w = 0; w < 4; w++) {
      u32 pk = tile32[d * 33 + c8 * 4 + w];
      v[2 * w] = (short)(u16)(pk & 0xFFFF);
      v[2 * w + 1] = (short)(u16)(pk >> 16);
    }
    *(s16x8*)(vT + ((size_t)bh * 64 + d) * 2048 + tb + c8 * 8) = v;
  }
}

// ---------------------------------------------------------------------------
// GEMM: C = A @ Bt^T + bias. MB x NT tile, BK=32 K steps. (R13-proven:
// MB=64 -> 6 blocks/CU; single-buffer skeleton; no swizzle/vmcnt asm.)
// ---------------------------------------------------------------------------
template <int MB, int NT, int KK, int ATILED>
__global__ __launch_bounds__(256, 6) void gemm_bt(
    const u16* __restrict__ A, int lda, const u16* __restrict__ Bt,
    const void* __restrict__ bias, const int* __restrict__ fI32,
    void* __restrict__ C, int ropeMode, int outF,
    const void* __restrict__ cost, const void* __restrict__ sint, int N) {
  constexpr int MT = MB / 32;    // m fragments per wave
  constexpr int NTW = NT / 32;   // n fragments per wave
  constexpr int KT = KK / 32;    // K steps
  constexpr int APW = MB / 64;   // A cp16 per wave per step
  constexpr int BPW = NT / 64;   // B cp16 per wave per step
  __shared__ __attribute__((aligned(16))) u16 As[MB * 32];
  __shared__ __attribute__((aligned(16))) u16 Bs[NT * 32];
  const int inf32 = *fI32;
  const int tid = threadIdx.x;
  const int wave = tid >> 6, lane = tid & 63, quad = lane >> 4, l16 = lane & 15;
  const int bx = blockIdx.x, by = blockIdx.y;
  const int m0 = by * MB, n0 = bx * NT;
  const int wm = (wave & 1) * (MB / 2), wn = (wave >> 1) * (NT / 2);
  f32x4 acc[MT][NTW];
#pragma unroll
  for (int i = 0; i < MT; i++)
#pragma unroll
    for (int j = 0; j < NTW; j++) acc[i][j] = (f32x4){0.f, 0.f, 0.f, 0.f};

  // staging source pointers (per-lane); LDS dests are wave-uniform.
  const u16* aT = nullptr;
  const u16* aP = nullptr;
  int halfA = 0;
  if constexpr (ATILED) {
    const int mB = (MB == 128) ? by : (by >> 1);
    halfA = (MB == 128) ? 0 : (by & 1);
    aT = A + (size_t)mB * KK * 128 + lane * 8;
  } else {
    const int lr = lane >> 2, lk = (lane & 3) * 8;
    aP = A + (size_t)(m0 + wave * (MB / 4) + lr) * lda + lk;
  }
  const u16* bT = Bt + (size_t)bx * KK * NT + lane * 8;

  for (int s = 0; s < KT; ++s) {
    __syncthreads();
    if constexpr (ATILED) {
#pragma unroll
      for (int j = 0; j < APW; j++) {
        const int c = wave * APW + j;
        size_t off;
        if constexpr (MB == 128) off = (size_t)s * 4096 + c * 512;
        else                     off = (size_t)s * 4096 + c * 1024 + halfA * 512;
        cp16(aT + off, As + c * 512);
      }
    } else {
      const int kb = s * 32;
#pragma unroll
      for (int j = 0; j < APW; j++)
        cp16(aP + kb + (size_t)(16 * j) * lda, As + wave * (APW * 512) + j * 512);
    }
#pragma unroll
    for (int j = 0; j < BPW; j++) {
      const int c = wave * BPW + j;
      cp16(bT + (size_t)s * (NT * 32) + c * 512, Bs + c * 512);
    }
    __syncthreads();
    s16x8 af[MT], bfr[NTW];
#pragma unroll
    for (int mt = 0; mt < MT; mt++) {
      if constexpr (ATILED)
        af[mt] = *(const s16x8*)(As + quad * (MB * 8) + (wm + mt * 16 + l16) * 8);
      else
        af[mt] = *(const s16x8*)(As + (wm + mt * 16 + l16) * 32 + quad * 8);
    }
#pragma unroll
    for (int nt = 0; nt < NTW; nt++)
      bfr[nt] = *(const s16x8*)(Bs + quad * (NT * 8) + (wn + nt * 16 + l16) * 8);
#pragma unroll
    for (int mt = 0; mt < MT; mt++)
#pragma unroll
      for (int nt = 0; nt < NTW; nt++)
        acc[mt][nt] = __builtin_amdgcn_mfma_f32_16x16x32_bf16(
            af[mt], bfr[nt], acc[mt][nt], 0, 0, 0);
  }

#pragma unroll
  for (int nt = 0; nt < NTW; nt++) {
    int col = n0 + wn + nt * 16 + l16;
    float bv = loadf(bias, col, inf32);
    if (ropeMode && col < 2048) {
      int j = (col & 63) >> 1, odd = col & 1;
#pragma unroll
      for (int mt = 0; mt < MT; mt++)
#pragma unroll
        for (int r = 0; r < 4; r++) {
          int row = m0 + wm + mt * 16 + quad * 4 + r, t = row & 2047;
          float cv = loadf(cost, (size_t)t * 32 + j, inf32);
          float sv = loadf(sint, (size_t)t * 32 + j, inf32);
          float val = acc[mt][nt][r] + bv;
          float pr = __shfl_xor(val, 1);
          float res = odd ? (pr * sv + val * cv) : (val * cv - pr * sv);
          ((u16*)C)[(size_t)row * N + col] = f2bf(res);
        }
    } else if (outF && inf32) {  // final output, fp32
#pragma unroll
      for (int mt = 0; mt < MT; mt++)
#pragma unroll
        for (int r = 0; r < 4; r++) {
          int row = m0 + wm + mt * 16 + quad * 4 + r;
          ((float*)C)[(size_t)row * N + col] = acc[mt][nt][r] + bv;
        }
    } else {
#pragma unroll
      for (int mt = 0; mt < MT; mt++)
#pragma unroll
        for (int r = 0; r < 4; r++) {
          int row = m0 + wm + mt * 16 + quad * 4 + r;
          ((u16*)C)[(size_t)row * N + col] = f2bf(acc[mt][nt][r] + bv);
        }
    }
  }
}

// ---------------------------------------------------------------------------
// Causal flash attention v6. R15 structure changes (numerics/swizzle
// unchanged from R14-verified v5):
//  - 1024 blocks x 256 threads (4 waves, 64 q-rows/block): 4 independent
//    barrier domains/CU (was 2), half-size convoys (R13 lever class).
//  - K/V LDS double-buffer: ONE barrier per chunk (was 2). Per iter:
//    {write chunk c+1 to buf[cur^1]; prefetch c+2 regs; compute c from
//    buf[cur]; barrier}. Write/read hazards on each buffer are separated by
//    exactly one barrier on both edges.
//  - 4-round balanced schedule: round 0..3 -> qt={15-p,p,15-p,p},
//    half={1,1,0,0}; per-CU chunk total = 66 for every p; heavy-first.
// LDS: 2x(8+8)KB K/V + 4x2KB P = 40KB -> 4 blocks/CU (16 waves/CU).
// XOR granule swizzle (R14-proven: conflicts 4.87M -> 0) kept bit-identical.
// ---------------------------------------------------------------------------
__device__ __forceinline__ int kvIdx(int chunk, int row) {  // 64-row tile
  return chunk * 512 + (((row & 56) | ((row ^ chunk) & 7)) << 3);
}
__device__ __forceinline__ int pIdx(int chunk, int row) {   // 16-row tile
  return chunk * 128 + (((row & 8) | ((row ^ chunk) & 7)) << 3);
}

__global__ __launch_bounds__(256, 4) void attn_kernel(u16* qkv,
                                                      const u16* __restrict__ vT) {
  __shared__ __attribute__((aligned(16))) u16 Ks[2][8 * 512];
  __shared__ __attribute__((aligned(16))) u16 Vt[2][8 * 512];
  __shared__ __attribute__((aligned(16))) u16 Pl[4][8 * 128];
  const int tid = threadIdx.x;
  const int wave = tid >> 6, lane = tid & 63, quad = lane >> 4, l16 = lane & 15;
  const int cu = blockIdx.x & 255, round = blockIdx.x >> 8;
  const int p = cu >> 5, bh = cu & 31;
  const int qt = (round & 1) ? p : 15 - p;
  const int half = 1 - (round >> 1);
  const int h = bh & 15;
  const size_t rb = (size_t)(bh >> 4) * 2048;
  const int q0 = qt * 128 + half * 64;  // block's 64-row q base
  const int mq = q0 + wave * 16;        // wave's first q row
  const float SCALE = 0.18033688011112042f;  // 0.125 * log2(e)

  // Q fragment for this wave's 16 rows (direct from global, once)
  s16x8 qa0, qa1;
  {
    const u16* qp = qkv + (rb + q0 + wave * 16 + l16) * 3072 + h * 64;
    qa0 = *(const s16x8*)(qp + quad * 8);
    qa1 = *(const s16x8*)(qp + 32 + quad * 8);
  }

  f32x4 o[4];
  float l_r[4] = {0.f, 0.f, 0.f, 0.f};
#pragma unroll
  for (int i = 0; i < 4; i++) o[i] = (f32x4){0.f, 0.f, 0.f, 0.f};

  const int nchunks = 2 * qt + half + 1;
  const int srow = tid >> 3, sc8 = tid & 7;  // rows srow, srow+32; granule sc8
  const int si0 = kvIdx(sc8, srow), si1 = kvIdx(sc8, srow + 32);
  const u16* kg = qkv + (rb + srow) * 3072 + 1024 + h * 64 + sc8 * 8;
  const u16* vg = vT + ((size_t)bh * 64 + srow) * 2048 + sc8 * 8;

  // prologue: chunk 0 -> regs -> buf0; prefetch chunk 1 regs
  s16x8 kr0, kr1, vr0, vr1;
  kr0 = *(const s16x8*)(kg);
  kr1 = *(const s16x8*)(kg + (size_t)32 * 3072);
  vr0 = *(const s16x8*)(vg);
  vr1 = *(const s16x8*)(vg + (size_t)32 * 2048);
  *(s16x8*)(&Ks[0][si0]) = kr0;
  *(s16x8*)(&Ks[0][si1]) = kr1;
  *(s16x8*)(&Vt[0][si0]) = vr0;
  *(s16x8*)(&Vt[0][si1]) = vr1;
  if (nchunks > 1) {
    kr0 = *(const s16x8*)(kg + (size_t)64 * 3072);
    kr1 = *(const s16x8*)(kg + (size_t)96 * 3072);
    vr0 = *(const s16x8*)(vg + 64);
    vr1 = *(const s16x8*)(vg + (size_t)32 * 2048 + 64);
  }
  __syncthreads();

  for (int c = 0; c < nchunks; c++) {
    const int sb = c * 64;
    const int cur = c & 1;
    if (c + 1 < nchunks) {
      // write chunk c+1 into the other buffer (its previous readers -- chunk
      // c-1's compute -- all passed the barrier at the end of iter c-1)
      *(s16x8*)(&Ks[cur ^ 1][si0]) = kr0;
      *(s16x8*)(&Ks[cur ^ 1][si1]) = kr1;
      *(s16x8*)(&Vt[cur ^ 1][si0]) = vr0;
      *(s16x8*)(&Vt[cur ^ 1][si1]) = vr1;
      if (c + 2 < nchunks) {  // prefetch chunk c+2 into regs
        const int nb = sb + 128;
        kr0 = *(const s16x8*)(kg + (size_t)nb * 3072);
        kr1 = *(const s16x8*)(kg + (size_t)(nb + 32) * 3072);
        vr0 = *(const s16x8*)(vg + nb);
        vr1 = *(const s16x8*)(vg + (size_t)32 * 2048 + nb);
      }
    }

    // waves whose query range is entirely below this key chunk contribute 0
    if (sb <= mq + 15) {
      f32x4 S[4];
#pragma unroll
      for (int kf = 0; kf < 4; kf++) {
        s16x8 k0 = *(const s16x8*)(&Ks[cur][kvIdx(quad, kf * 16 + l16)]);
        s16x8 k1 = *(const s16x8*)(&Ks[cur][kvIdx(quad + 4, kf * 16 + l16)]);
        f32x4 a = (f32x4){0.f, 0.f, 0.f, 0.f};
        a = __builtin_amdgcn_mfma_f32_16x16x32_bf16(qa0, k0, a, 0, 0, 0);
        a = __builtin_amdgcn_mfma_f32_16x16x32_bf16(qa1, k1, a, 0, 0, 0);
        S[kf] = a;
      }

      // exp, mask-select, per-lane l accumulation, P write, single wait
      u16* P = Pl[wave];
      const bool needMask = (sb + 63) > mq;  // wave-uniform
#pragma unroll
      for (int r = 0; r < 4; r++) {
        const int qi = mq + quad * 4 + r;
#pragma unroll
        for (int kf = 0; kf < 4; kf++) {
          float pv = __builtin_amdgcn_exp2f(S[kf][r] * SCALE);
          if (needMask) pv = ((sb + kf * 16 + l16) <= qi) ? pv : 0.f;
          l_r[r] += pv;
          P[pIdx(kf * 2 + (l16 >> 3), quad * 4 + r) + (l16 & 7)] = f2bf_fast(pv);
        }
      }
      asm volatile("s_waitcnt lgkmcnt(0)" ::: "memory");
      s16x8 pa0 = *(const s16x8*)(P + pIdx(quad, l16));
      s16x8 pa1 = *(const s16x8*)(P + pIdx(quad + 4, l16));

#pragma unroll
      for (int dt = 0; dt < 4; dt++) {
        s16x8 vb0 = *(const s16x8*)(&Vt[cur][kvIdx(quad, dt * 16 + l16)]);
        s16x8 vb1 = *(const s16x8*)(&Vt[cur][kvIdx(quad + 4, dt * 16 + l16)]);
        o[dt] = __builtin_amdgcn_mfma_f32_16x16x32_bf16(pa0, vb0, o[dt], 0, 0, 0);
        o[dt] = __builtin_amdgcn_mfma_f32_16x16x32_bf16(pa1, vb1, o[dt], 0, 0, 0);
      }
    }
    __syncthreads();  // buf[cur] readers done; buf[cur^1] writes visible
  }

  // deferred cross-lane l reduction + y write into qkv's V columns
  float inv[4];
#pragma unroll
  for (int r = 0; r < 4; r++) {
    float rs = l_r[r];
#pragma unroll
    for (int off = 8; off; off >>= 1) rs += __shfl_xor(rs, off);
    inv[r] = 1.0f / fmaxf(rs, 1e-30f);
  }
#pragma unroll
  for (int dt = 0; dt < 4; dt++)
#pragma unroll
    for (int r = 0; r < 4; r++)
      qkv[(rb + mq + quad * 4 + r) * 3072 + 2048 + h * 64 +
          dt * 16 + l16] = f2bf(o[dt][r] * inv[r]);
}

extern "C" void kernel_launch(void* const* d_in, const int* in_sizes, int n_in,
                              void* d_out, int out_size, void* d_ws,
                              size_t ws_size, hipStream_t stream) {
  const void* x = d_in[0];
  const void* Wqkv = d_in[1];
  const void* bqkv = d_in[2];
  const void* Wproj = d_in[3];
  const void* bproj = d_in[4];
  const void* cost = d_in[5];
  const void* sint = d_in[6];

  int* flags = (int*)d_ws;
  u16* WqkvT = (u16*)d_ws + 128;               // tiled [24][32][4][128][8]
  u16* WprojT = WqkvT + (size_t)3072 * 1024;   // tiled [16][32][4][64][8]
  u16* qkv = WprojT + (size_t)1024 * 1024;     // [4096][3072] bf16 row-major
  u16* yb = qkv + 2048;                        // y = V-columns of qkv (dead
                                               //   after transposeV), lda 3072
  u16* xb = (u16*)d_out;                       // tiled [32][32][4][128][8]
  u16* vT = (u16*)d_out + (size_t)4096 * 1024; // V^T (upper half; dead before
                                               //   final fp32 write)

  detect_dtype<<<1, 64, 0, stream>>>((const u16*)x, flags);
  convert_x<<<2048, 256, 0, stream>>>(x, flags, xb);
  transposeW2<<<dim3(64, 16), 256, 0, stream>>>(Wqkv, Wproj, flags, WqkvT,
                                                WprojT);
  gemm_bt<64, 128, 1024, 1><<<dim3(24, 64), 256, 0, stream>>>(
      xb, 1024, WqkvT, bqkv, flags, qkv, 1, 0, cost, sint, 3072);
  transposeV<<<dim3(32, 32), 256, 0, stream>>>(qkv, vT);
  attn_kernel<<<1024, 256, 0, stream>>>(qkv, vT);
  gemm_bt<64, 64, 1024, 0><<<dim3(16, 64), 256, 0, stream>>>(
      yb, 3072, WprojT, bproj, flags, d_out, 0, 1, nullptr, nullptr, 1024);
}

// Round 9
// 212.486 us; speedup vs baseline: 1.0026x; 1.0026x over previous
//
#include <hip/hip_runtime.h>
#include <stdint.h>

typedef short s16x8 __attribute__((ext_vector_type(8)));
typedef float f32x4 __attribute__((ext_vector_type(4)));
typedef unsigned short u16;
typedef unsigned int u32;

__device__ __forceinline__ float bf2f(u16 u) {
  union { u32 i; float f; } v; v.i = ((u32)u) << 16; return v.f;
}
__device__ __forceinline__ u16 f2bf(float f) {  // round-to-nearest-even
  union { float f; u32 i; } v; v.f = f;
  u32 i = v.i;
  return (u16)((i + 0x7fffu + ((i >> 16) & 1u)) >> 16);
}
__device__ __forceinline__ u16 f2bf_fast(float f) {  // round-half-up
  union { float f; u32 i; } v; v.f = f;
  return (u16)((v.i + 0x8000u) >> 16);
}

__device__ __forceinline__ s16x8 load8(const void* p, size_t idx, int isf32) {
  s16x8 r;
  if (isf32) {
    const float* f = (const float*)p + idx;
    f32x4 a = *(const f32x4*)f;
    f32x4 b = *(const f32x4*)(f + 4);
#pragma unroll
    for (int j = 0; j < 4; j++) {
      r[j] = (short)f2bf(a[j]);
      r[4 + j] = (short)f2bf(b[j]);
    }
  } else {
    r = *(const s16x8*)((const u16*)p + idx);
  }
  return r;
}
__device__ __forceinline__ float loadf(const void* p, size_t idx, int isf32) {
  return isf32 ? ((const float*)p)[idx] : bf2f(((const u16*)p)[idx]);
}

// async global->LDS 16B/lane; LDS dest = wave-uniform base + lane*16.
__device__ __forceinline__ void cp16(const u16* g, u16* l) {
  __builtin_amdgcn_global_load_lds(
      (const __attribute__((address_space(1))) u32*)g,
      (__attribute__((address_space(3))) u32*)l, 16, 0, 0);
}

// ---------------------------------------------------------------------------
// Dtype detector (R3-proven): flags[0]=1 if inputs fp32, flags[1]=0.
// ---------------------------------------------------------------------------
__global__ void detect_dtype(const u16* __restrict__ x, int* __restrict__ flags) {
  int cnt = 0;
  for (int i = threadIdx.x; i < 4096; i += 64) {
    int e = (x[i] >> 7) & 0xFF;
    if (e >= 0xF0) cnt++;
  }
  unsigned long long any = __ballot(cnt > 0);
  if (threadIdx.x == 0) {
    flags[0] = (any != 0ull) ? 1 : 0;
    flags[1] = 0;
  }
}

// ---------------------------------------------------------------------------
// convert_x -> TILED bf16 layout: xb_t[mB][kB][kq][r][8], tile = 128 rows x
// 32 k (8KB). Writes contiguous (tid*8).
// ---------------------------------------------------------------------------
__global__ __launch_bounds__(256) void convert_x(const void* __restrict__ x,
                                                 const int* __restrict__ fp,
                                                 u16* __restrict__ xb) {
  int tid = blockIdx.x * 256 + threadIdx.x;  // 0..524287
  int r = tid & 127, kq = (tid >> 7) & 3, kB = (tid >> 9) & 31, mB = tid >> 14;
  size_t src = (size_t)(mB * 128 + r) * 1024 + kB * 32 + kq * 8;
  *(s16x8*)(xb + (size_t)tid * 8) = load8(x, src, *fp);
}

// ---------------------------------------------------------------------------
// Fused weight transposes into TILED layouts:
//   WqkvT_t[nB(24)][kB(32)][kq(4)][r(128)][8]   (tile rows = 128, for NT=128)
//   WprojT_t[nB(16)][kB(32)][kq(4)][r(64)][8]   (tile rows = 64,  for NT=64)
// u32-packed conflict-free LDS transpose (R4-proven core); n-fast store order
// keeps 64-thread groups writing 1KB contiguous. grid (48+16, 16).
// ---------------------------------------------------------------------------
__global__ __launch_bounds__(256) void transposeW2(
    const void* __restrict__ Wqkv, const void* __restrict__ Wproj,
    const int* __restrict__ fp, u16* __restrict__ WqkvT,
    u16* __restrict__ WprojT) {
  __shared__ u32 tile32[32 * 66];
  const int f = *fp;
  const int tid = threadIdx.x;
  const int bx = blockIdx.x;
  const void* W;
  u16* WT;
  int N, nb, qkvSide;
  if (bx < 48) { W = Wqkv; WT = WqkvT; N = 3072; nb = bx * 64; qkvSide = 1; }
  else         { W = Wproj; WT = WprojT; N = 1024; nb = (bx - 48) * 64; qkvSide = 0; }
  const int kb = blockIdx.y * 64;  // K = 1024
  {
    int a = tid >> 3, c8 = tid & 7;
    s16x8 r0 = load8(W, (size_t)(kb + 2 * a) * N + nb + c8 * 8, f);
    s16x8 r1 = load8(W, (size_t)(kb + 2 * a + 1) * N + nb + c8 * 8, f);
#pragma unroll
    for (int j = 0; j < 8; j++)
      tile32[a * 66 + c8 * 8 + j] = (u32)(u16)r0[j] | ((u32)(u16)r1[j] << 16);
  }
  __syncthreads();
#pragma unroll
  for (int i = 0; i < 2; i++) {
    int idx = tid + i * 256;
    int n = idx & 63, c8 = idx >> 6;  // n fast -> contiguous tiled stores
    s16x8 v;
#pragma unroll
    for (int w = 0; w < 4; w++) {
      u32 pk = tile32[(c8 * 4 + w) * 66 + n];
      v[2 * w] = (short)(u16)(pk & 0xFFFF);
      v[2 * w + 1] = (short)(u16)(pk >> 16);
    }
    int R = nb + n, k = kb + c8 * 8;
    int kB = k >> 5, kq = (k >> 3) & 3;
    size_t off;
    if (qkvSide) {
      int nB = R >> 7, r = R & 127;
      off = ((size_t)(nB * 32 + kB) * 4 + kq) * 1024 + r * 8;
    } else {
      int nB = R >> 6, r = R & 63;
      off = (size_t)(nB * 32 + kB) * 2048 + kq * 512 + r * 8;
    }
    *(s16x8*)(WT + off) = v;
  }
}

// ---------------------------------------------------------------------------
// V transpose: qkv V cols -> vT[bh*64+d][2048] (R6-proven, conflict-free).
// ---------------------------------------------------------------------------
__global__ __launch_bounds__(256) void transposeV(const u16* __restrict__ qkv,
                                                  u16* __restrict__ vT) {
  __shared__ u32 tile32[64 * 33];
  const int tid = threadIdx.x;
  const int tb = blockIdx.x * 64, bh = blockIdx.y;
  const int b = bh >> 4, h = bh & 15;
  {
    int a = tid >> 3, c8 = tid & 7;
    const u16* base = qkv + (size_t)(b * 2048 + tb + 2 * a) * 3072 + 2048 + h * 64;
    s16x8 r0 = *(const s16x8*)(base + c8 * 8);
    s16x8 r1 = *(const s16x8*)(base + 3072 + c8 * 8);
#pragma unroll
    for (int j = 0; j < 8; j++)
      tile32[(c8 * 8 + j) * 33 + a] = (u32)(u16)r0[j] | ((u32)(u16)r1[j] << 16);
  }
  __syncthreads();
#pragma unroll
  for (int i = 0; i < 2; i++) {
    int idx = tid + i * 256;
    int d = idx >> 3, c8 = idx & 7;
    s16x8 v;
#pragma unroll
    for (int w = 0; w < 4; w++) {
      u32 pk = tile32[d * 33 + c8 * 4 + w];
      v[2 * w] = (short)(u16)(pk & 0xFFFF);
      v[2 * w + 1] = (short)(u16)(pk >> 16);
    }
    *(s16x8*)(vT + ((size_t)bh * 64 + d) * 2048 + tb + c8 * 8) = v;
  }
}

// ---------------------------------------------------------------------------
// GEMM: C = A @ Bt^T + bias. MB x NT tile, BK-wide K steps (KSUB 32-k chunks
// per step). R16 = R13-proven skeleton (single LDS buffer, syncthreads ->
// stage -> syncthreads -> compute; MB=64 -> 6 blocks/CU; no swizzle, no
// vmcnt asm) with BK=64: halves barrier-drain count 32 -> 16, doubles
// MFMA per step. (BK=64 previously tested only confounded with the
// regressive XCD swizzle in R12; clean test here.)
// ATILED=1: A pre-tiled [mB][kB][kq][r(128)][8]; ATILED=0: A row-major.
// ---------------------------------------------------------------------------
template <int MB, int NT, int KK, int ATILED, int BK>
__global__ __launch_bounds__(256, 6) void gemm_bt(
    const u16* __restrict__ A, int lda, const u16* __restrict__ Bt,
    const void* __restrict__ bias, const int* __restrict__ fI32,
    void* __restrict__ C, int ropeMode, int outF,
    const void* __restrict__ cost, const void* __restrict__ sint, int N) {
  constexpr int MT = MB / 32;    // m fragments per wave
  constexpr int NTW = NT / 32;   // n fragments per wave
  constexpr int KSUB = BK / 32;  // 32-k chunks per step
  constexpr int KT = KK / BK;    // K steps
  constexpr int APW = MB / 64;   // A cp16 per wave per 32-k chunk
  constexpr int BPW = NT / 64;   // B cp16 per wave per 32-k chunk
  __shared__ __attribute__((aligned(16))) u16 As[KSUB * MB * 32];
  __shared__ __attribute__((aligned(16))) u16 Bs[KSUB * NT * 32];
  const int inf32 = *fI32;
  const int tid = threadIdx.x;
  const int wave = tid >> 6, lane = tid & 63, quad = lane >> 4, l16 = lane & 15;
  const int bx = blockIdx.x, by = blockIdx.y;
  const int m0 = by * MB, n0 = bx * NT;
  const int wm = (wave & 1) * (MB / 2), wn = (wave >> 1) * (NT / 2);
  f32x4 acc[MT][NTW];
#pragma unroll
  for (int i = 0; i < MT; i++)
#pragma unroll
    for (int j = 0; j < NTW; j++) acc[i][j] = (f32x4){0.f, 0.f, 0.f, 0.f};

  // staging source pointers (per-lane); LDS dests are wave-uniform.
  const u16* aT = nullptr;
  const u16* aP = nullptr;
  int halfA = 0;
  if constexpr (ATILED) {
    const int mB = (MB == 128) ? by : (by >> 1);
    halfA = (MB == 128) ? 0 : (by & 1);
    aT = A + (size_t)mB * KK * 128 + lane * 8;
  } else {
    const int lr = lane >> 2, lk = (lane & 3) * 8;
    aP = A + (size_t)(m0 + wave * (MB / 4) + lr) * lda + lk;
  }
  const u16* bT = Bt + (size_t)bx * KK * NT + lane * 8;

  for (int s = 0; s < KT; ++s) {
    __syncthreads();
#pragma unroll
    for (int ks = 0; ks < KSUB; ks++) {
      const int kb32 = s * KSUB + ks;  // global 32-k block index
      if constexpr (ATILED) {
#pragma unroll
        for (int j = 0; j < APW; j++) {
          const int c = wave * APW + j;
          size_t off;
          if constexpr (MB == 128) off = (size_t)kb32 * 4096 + c * 512;
          else                     off = (size_t)kb32 * 4096 + c * 1024 + halfA * 512;
          cp16(aT + off, As + ks * (MB * 32) + c * 512);
        }
      } else {
#pragma unroll
        for (int j = 0; j < APW; j++)
          cp16(aP + kb32 * 32 + (size_t)(16 * j) * lda,
               As + ks * (MB * 32) + wave * (APW * 512) + j * 512);
      }
#pragma unroll
      for (int j = 0; j < BPW; j++) {
        const int c = wave * BPW + j;
        cp16(bT + (size_t)kb32 * (NT * 32) + c * 512,
             Bs + ks * (NT * 32) + c * 512);
      }
    }
    __syncthreads();
#pragma unroll
    for (int ks = 0; ks < KSUB; ks++) {
      s16x8 af[MT], bfr[NTW];
#pragma unroll
      for (int mt = 0; mt < MT; mt++) {
        if constexpr (ATILED)
          af[mt] = *(const s16x8*)(As + ks * (MB * 32) + quad * (MB * 8) +
                                   (wm + mt * 16 + l16) * 8);
        else
          af[mt] = *(const s16x8*)(As + ks * (MB * 32) +
                                   (wm + mt * 16 + l16) * 32 + quad * 8);
      }
#pragma unroll
      for (int nt = 0; nt < NTW; nt++)
        bfr[nt] = *(const s16x8*)(Bs + ks * (NT * 32) + quad * (NT * 8) +
                                  (wn + nt * 16 + l16) * 8);
#pragma unroll
      for (int mt = 0; mt < MT; mt++)
#pragma unroll
        for (int nt = 0; nt < NTW; nt++)
          acc[mt][nt] = __builtin_amdgcn_mfma_f32_16x16x32_bf16(
              af[mt], bfr[nt], acc[mt][nt], 0, 0, 0);
    }
  }

#pragma unroll
  for (int nt = 0; nt < NTW; nt++) {
    int col = n0 + wn + nt * 16 + l16;
    float bv = loadf(bias, col, inf32);
    if (ropeMode && col < 2048) {
      int j = (col & 63) >> 1, odd = col & 1;
#pragma unroll
      for (int mt = 0; mt < MT; mt++)
#pragma unroll
        for (int r = 0; r < 4; r++) {
          int row = m0 + wm + mt * 16 + quad * 4 + r, t = row & 2047;
          float cv = loadf(cost, (size_t)t * 32 + j, inf32);
          float sv = loadf(sint, (size_t)t * 32 + j, inf32);
          float val = acc[mt][nt][r] + bv;
          float pr = __shfl_xor(val, 1);
          float res = odd ? (pr * sv + val * cv) : (val * cv - pr * sv);
          ((u16*)C)[(size_t)row * N + col] = f2bf(res);
        }
    } else if (outF && inf32) {  // final output, fp32
#pragma unroll
      for (int mt = 0; mt < MT; mt++)
#pragma unroll
        for (int r = 0; r < 4; r++) {
          int row = m0 + wm + mt * 16 + quad * 4 + r;
          ((float*)C)[(size_t)row * N + col] = acc[mt][nt][r] + bv;
        }
    } else {
#pragma unroll
      for (int mt = 0; mt < MT; mt++)
#pragma unroll
        for (int r = 0; r < 4; r++) {
          int row = m0 + wm + mt * 16 + quad * 4 + r;
          ((u16*)C)[(size_t)row * N + col] = f2bf(acc[mt][nt][r] + bv);
        }
    }
  }
}

// ---------------------------------------------------------------------------
// Causal flash attention v5 (exact R14-proven version, 44.3us; conflicts 0).
// 512 threads = 8 waves, 16 Q rows/wave, 128-row blocks, 64-key chunks,
// fixed-base softmax with deferred l-reduction. K/V register-prefetch
// double-buffer; 2 barriers/chunk. Chunked granule LDS [dchunk][row][8] with
// XOR slot swizzle slot=(row&56)|((row^chunk)&7). LDS 32KB; 2 blocks/CU.
// (R15's 4-wave/1-barrier variant regressed: occupancy never rose.)
// ---------------------------------------------------------------------------
__device__ __forceinline__ int kvIdx(int chunk, int row) {  // 64-row tile
  return chunk * 512 + (((row & 56) | ((row ^ chunk) & 7)) << 3);
}
__device__ __forceinline__ int pIdx(int chunk, int row) {   // 16-row tile
  return chunk * 128 + (((row & 8) | ((row ^ chunk) & 7)) << 3);
}

__global__ __launch_bounds__(512) void attn_kernel(u16* qkv,
                                                   const u16* __restrict__ vT) {
  __shared__ __attribute__((aligned(16))) u16 Ks[8 * 512];
  __shared__ __attribute__((aligned(16))) u16 Vt[8 * 512];
  __shared__ __attribute__((aligned(16))) u16 Pl[8][8 * 128];
  const int tid = threadIdx.x;
  const int wave = tid >> 6, lane = tid & 63, quad = lane >> 4, l16 = lane & 15;
  const int cu = blockIdx.x & 255, round = blockIdx.x >> 8;
  const int p = cu >> 5, bh = cu & 31;
  const int qt = round ? p : 15 - p;  // heavy first
  const int h = bh & 15;
  const size_t rb = (size_t)(bh >> 4) * 2048;
  const int qb = qt * 128;
  const float SCALE = 0.18033688011112042f;  // 0.125 * log2(e)

  // Q fragment for this wave's 16 rows (direct from global, once)
  s16x8 qa0, qa1;
  {
    const u16* qp = qkv + (rb + qb + wave * 16 + l16) * 3072 + h * 64;
    qa0 = *(const s16x8*)(qp + quad * 8);
    qa1 = *(const s16x8*)(qp + 32 + quad * 8);
  }

  f32x4 o[4];
  float l_r[4] = {0.f, 0.f, 0.f, 0.f};
#pragma unroll
  for (int i = 0; i < 4; i++) o[i] = (f32x4){0.f, 0.f, 0.f, 0.f};

  const int nchunks = 2 * qt + 2;
  const int srow = tid >> 3, sc8 = tid & 7;  // 64 rows x 8 d-chunks staging
  const int stIdx = kvIdx(sc8, srow);        // swizzled staging granule
  s16x8 kr, vr;
  {
    kr = *(const s16x8*)(qkv + (rb + srow) * 3072 + 1024 + h * 64 + sc8 * 8);
    vr = *(const s16x8*)(vT + ((size_t)bh * 64 + srow) * 2048 + sc8 * 8);
  }

  for (int c = 0; c < nchunks; c++) {
    const int sb = c * 64;
    __syncthreads();  // previous compute done reading Ks/Vt
    *(s16x8*)(Ks + stIdx) = kr;
    *(s16x8*)(Vt + stIdx) = vr;
    __syncthreads();
    if (c + 1 < nchunks) {  // next chunk's global loads overlap compute
      const int nb = sb + 64;
      kr = *(const s16x8*)(qkv + (rb + nb + srow) * 3072 + 1024 + h * 64 +
                           sc8 * 8);
      vr = *(const s16x8*)(vT + ((size_t)bh * 64 + srow) * 2048 + nb + sc8 * 8);
    }

    // waves whose query range is entirely below this key chunk contribute 0
    if (sb > qb + wave * 16 + 15) continue;

    f32x4 S[4];
#pragma unroll
    for (int kf = 0; kf < 4; kf++) {
      s16x8 k0 = *(const s16x8*)(Ks + kvIdx(quad, kf * 16 + l16));
      s16x8 k1 = *(const s16x8*)(Ks + kvIdx(quad + 4, kf * 16 + l16));
      f32x4 a = (f32x4){0.f, 0.f, 0.f, 0.f};
      a = __builtin_amdgcn_mfma_f32_16x16x32_bf16(qa0, k0, a, 0, 0, 0);
      a = __builtin_amdgcn_mfma_f32_16x16x32_bf16(qa1, k1, a, 0, 0, 0);
      S[kf] = a;
    }

    // exp, mask-select, per-lane l accumulation, P write, single wait
    u16* P = Pl[wave];
    const int mq = qb + wave * 16;
    const bool needMask = (sb + 63) > mq;  // wave-uniform
#pragma unroll
    for (int r = 0; r < 4; r++) {
      const int qi = mq + quad * 4 + r;
#pragma unroll
      for (int kf = 0; kf < 4; kf++) {
        float pv = __builtin_amdgcn_exp2f(S[kf][r] * SCALE);
        if (needMask) pv = ((sb + kf * 16 + l16) <= qi) ? pv : 0.f;
        l_r[r] += pv;
        P[pIdx(kf * 2 + (l16 >> 3), quad * 4 + r) + (l16 & 7)] = f2bf_fast(pv);
      }
    }
    asm volatile("s_waitcnt lgkmcnt(0)" ::: "memory");
    s16x8 pa0 = *(const s16x8*)(P + pIdx(quad, l16));
    s16x8 pa1 = *(const s16x8*)(P + pIdx(quad + 4, l16));

#pragma unroll
    for (int dt = 0; dt < 4; dt++) {
      s16x8 vb0 = *(const s16x8*)(Vt + kvIdx(quad, dt * 16 + l16));
      s16x8 vb1 = *(const s16x8*)(Vt + kvIdx(quad + 4, dt * 16 + l16));
      o[dt] = __builtin_amdgcn_mfma_f32_16x16x32_bf16(pa0, vb0, o[dt], 0, 0, 0);
      o[dt] = __builtin_amdgcn_mfma_f32_16x16x32_bf16(pa1, vb1, o[dt], 0, 0, 0);
    }
  }

  // deferred cross-lane l reduction + y write into qkv's V columns
  float inv[4];
#pragma unroll
  for (int r = 0; r < 4; r++) {
    float rs = l_r[r];
#pragma unroll
    for (int off = 8; off; off >>= 1) rs += __shfl_xor(rs, off);
    inv[r] = 1.0f / fmaxf(rs, 1e-30f);
  }
#pragma unroll
  for (int dt = 0; dt < 4; dt++)
#pragma unroll
    for (int r = 0; r < 4; r++)
      qkv[(rb + qb + wave * 16 + quad * 4 + r) * 3072 + 2048 + h * 64 +
          dt * 16 + l16] = f2bf(o[dt][r] * inv[r]);
}

extern "C" void kernel_launch(void* const* d_in, const int* in_sizes, int n_in,
                              void* d_out, int out_size, void* d_ws,
                              size_t ws_size, hipStream_t stream) {
  const void* x = d_in[0];
  const void* Wqkv = d_in[1];
  const void* bqkv = d_in[2];
  const void* Wproj = d_in[3];
  const void* bproj = d_in[4];
  const void* cost = d_in[5];
  const void* sint = d_in[6];

  int* flags = (int*)d_ws;
  u16* WqkvT = (u16*)d_ws + 128;               // tiled [24][32][4][128][8]
  u16* WprojT = WqkvT + (size_t)3072 * 1024;   // tiled [16][32][4][64][8]
  u16* qkv = WprojT + (size_t)1024 * 1024;     // [4096][3072] bf16 row-major
  u16* yb = qkv + 2048;                        // y = V-columns of qkv (dead
                                               //   after transposeV), lda 3072
  u16* xb = (u16*)d_out;                       // tiled [32][32][4][128][8]
  u16* vT = (u16*)d_out + (size_t)4096 * 1024; // V^T (upper half; dead before
                                               //   final fp32 write)

  detect_dtype<<<1, 64, 0, stream>>>((const u16*)x, flags);
  convert_x<<<2048, 256, 0, stream>>>(x, flags, xb);
  transposeW2<<<dim3(64, 16), 256, 0, stream>>>(Wqkv, Wproj, flags, WqkvT,
                                                WprojT);
  gemm_bt<64, 128, 1024, 1, 64><<<dim3(24, 64), 256, 0, stream>>>(
      xb, 1024, WqkvT, bqkv, flags, qkv, 1, 0, cost, sint, 3072);
  transposeV<<<dim3(32, 32), 256, 0, stream>>>(qkv, vT);
  attn_kernel<<<512, 512, 0, stream>>>(qkv, vT);
  gemm_bt<64, 64, 1024, 0, 64><<<dim3(16, 64), 256, 0, stream>>>(
      yb, 3072, WprojT, bproj, flags, d_out, 0, 1, nullptr, nullptr, 1024);
}

// Round 10
// 198.137 us; speedup vs baseline: 1.0752x; 1.0724x over previous
//
#include <hip/hip_runtime.h>
#include <stdint.h>

typedef short s16x8 __attribute__((ext_vector_type(8)));
typedef float f32x4 __attribute__((ext_vector_type(4)));
typedef unsigned short u16;
typedef unsigned int u32;

__device__ __forceinline__ float bf2f(u16 u) {
  union { u32 i; float f; } v; v.i = ((u32)u) << 16; return v.f;
}
__device__ __forceinline__ u16 f2bf(float f) {  // round-to-nearest-even
  union { float f; u32 i; } v; v.f = f;
  u32 i = v.i;
  return (u16)((i + 0x7fffu + ((i >> 16) & 1u)) >> 16);
}
__device__ __forceinline__ u16 f2bf_fast(float f) {  // round-half-up
  union { float f; u32 i; } v; v.f = f;
  return (u16)((v.i + 0x8000u) >> 16);
}

__device__ __forceinline__ s16x8 load8(const void* p, size_t idx, int isf32) {
  s16x8 r;
  if (isf32) {
    const float* f = (const float*)p + idx;
    f32x4 a = *(const f32x4*)f;
    f32x4 b = *(const f32x4*)(f + 4);
#pragma unroll
    for (int j = 0; j < 4; j++) {
      r[j] = (short)f2bf(a[j]);
      r[4 + j] = (short)f2bf(b[j]);
    }
  } else {
    r = *(const s16x8*)((const u16*)p + idx);
  }
  return r;
}
__device__ __forceinline__ float loadf(const void* p, size_t idx, int isf32) {
  return isf32 ? ((const float*)p)[idx] : bf2f(((const u16*)p)[idx]);
}

// async global->LDS 16B/lane; LDS dest = wave-uniform base + lane*16.
__device__ __forceinline__ void cp16(const u16* g, u16* l) {
  __builtin_amdgcn_global_load_lds(
      (const __attribute__((address_space(1))) u32*)g,
      (__attribute__((address_space(3))) u32*)l, 16, 0, 0);
}

// ---------------------------------------------------------------------------
// Dtype detector (R3-proven): flags[0]=1 if inputs fp32, flags[1]=0.
// ---------------------------------------------------------------------------
__global__ void detect_dtype(const u16* __restrict__ x, int* __restrict__ flags) {
  int cnt = 0;
  for (int i = threadIdx.x; i < 4096; i += 64) {
    int e = (x[i] >> 7) & 0xFF;
    if (e >= 0xF0) cnt++;
  }
  unsigned long long any = __ballot(cnt > 0);
  if (threadIdx.x == 0) {
    flags[0] = (any != 0ull) ? 1 : 0;
    flags[1] = 0;
  }
}

// ---------------------------------------------------------------------------
// convert_x -> TILED bf16 layout: xb_t[mB][kB][kq][r][8], tile = 128 rows x
// 32 k (8KB). Writes contiguous (tid*8).
// ---------------------------------------------------------------------------
__global__ __launch_bounds__(256) void convert_x(const void* __restrict__ x,
                                                 const int* __restrict__ fp,
                                                 u16* __restrict__ xb) {
  int tid = blockIdx.x * 256 + threadIdx.x;  // 0..524287
  int r = tid & 127, kq = (tid >> 7) & 3, kB = (tid >> 9) & 31, mB = tid >> 14;
  size_t src = (size_t)(mB * 128 + r) * 1024 + kB * 32 + kq * 8;
  *(s16x8*)(xb + (size_t)tid * 8) = load8(x, src, *fp);
}

// ---------------------------------------------------------------------------
// Fused weight transposes into TILED layouts:
//   WqkvT_t[nB(24)][kB(32)][kq(4)][r(128)][8]   (tile rows = 128, for NT=128)
//   WprojT_t[nB(16)][kB(32)][kq(4)][r(64)][8]   (tile rows = 64,  for NT=64)
// u32-packed conflict-free LDS transpose (R4-proven core); n-fast store order
// keeps 64-thread groups writing 1KB contiguous. grid (48+16, 16).
// ---------------------------------------------------------------------------
__global__ __launch_bounds__(256) void transposeW2(
    const void* __restrict__ Wqkv, const void* __restrict__ Wproj,
    const int* __restrict__ fp, u16* __restrict__ WqkvT,
    u16* __restrict__ WprojT) {
  __shared__ u32 tile32[32 * 66];
  const int f = *fp;
  const int tid = threadIdx.x;
  const int bx = blockIdx.x;
  const void* W;
  u16* WT;
  int N, nb, qkvSide;
  if (bx < 48) { W = Wqkv; WT = WqkvT; N = 3072; nb = bx * 64; qkvSide = 1; }
  else         { W = Wproj; WT = WprojT; N = 1024; nb = (bx - 48) * 64; qkvSide = 0; }
  const int kb = blockIdx.y * 64;  // K = 1024
  {
    int a = tid >> 3, c8 = tid & 7;
    s16x8 r0 = load8(W, (size_t)(kb + 2 * a) * N + nb + c8 * 8, f);
    s16x8 r1 = load8(W, (size_t)(kb + 2 * a + 1) * N + nb + c8 * 8, f);
#pragma unroll
    for (int j = 0; j < 8; j++)
      tile32[a * 66 + c8 * 8 + j] = (u32)(u16)r0[j] | ((u32)(u16)r1[j] << 16);
  }
  __syncthreads();
#pragma unroll
  for (int i = 0; i < 2; i++) {
    int idx = tid + i * 256;
    int n = idx & 63, c8 = idx >> 6;  // n fast -> contiguous tiled stores
    s16x8 v;
#pragma unroll
    for (int w = 0; w < 4; w++) {
      u32 pk = tile32[(c8 * 4 + w) * 66 + n];
      v[2 * w] = (short)(u16)(pk & 0xFFFF);
      v[2 * w + 1] = (short)(u16)(pk >> 16);
    }
    int R = nb + n, k = kb + c8 * 8;
    int kB = k >> 5, kq = (k >> 3) & 3;
    size_t off;
    if (qkvSide) {
      int nB = R >> 7, r = R & 127;
      off = ((size_t)(nB * 32 + kB) * 4 + kq) * 1024 + r * 8;
    } else {
      int nB = R >> 6, r = R & 63;
      off = (size_t)(nB * 32 + kB) * 2048 + kq * 512 + r * 8;
    }
    *(s16x8*)(WT + off) = v;
  }
}

// ---------------------------------------------------------------------------
// V transpose: qkv V cols -> vT[bh*64+d][2048] (R6-proven, conflict-free).
// ---------------------------------------------------------------------------
__global__ __launch_bounds__(256) void transposeV(const u16* __restrict__ qkv,
                                                  u16* __restrict__ vT) {
  __shared__ u32 tile32[64 * 33];
  const int tid = threadIdx.x;
  const int tb = blockIdx.x * 64, bh = blockIdx.y;
  const int b = bh >> 4, h = bh & 15;
  {
    int a = tid >> 3, c8 = tid & 7;
    const u16* base = qkv + (size_t)(b * 2048 + tb + 2 * a) * 3072 + 2048 + h * 64;
    s16x8 r0 = *(const s16x8*)(base + c8 * 8);
    s16x8 r1 = *(const s16x8*)(base + 3072 + c8 * 8);
#pragma unroll
    for (int j = 0; j < 8; j++)
      tile32[(c8 * 8 + j) * 33 + a] = (u32)(u16)r0[j] | ((u32)(u16)r1[j] << 16);
  }
  __syncthreads();
#pragma unroll
  for (int i = 0; i < 2; i++) {
    int idx = tid + i * 256;
    int d = idx >> 3, c8 = idx & 7;
    s16x8 v;
#pragma unroll
    for (int w = 0; w < 4; w++) {
      u32 pk = tile32[d * 33 + c8 * 4 + w];
      v[2 * w] = (short)(u16)(pk & 0xFFFF);
      v[2 * w + 1] = (short)(u16)(pk >> 16);
    }
    *(s16x8*)(vT + ((size_t)bh * 64 + d) * 2048 + tb + c8 * 8) = v;
  }
}

// ---------------------------------------------------------------------------
// GEMM: C = A @ Bt^T + bias. MB x NT tile, BK-wide K steps. R16-proven
// skeleton (single LDS buffer, MB=64 -> 6 blocks/CU, BK=64, no swizzle/asm).
// ATILED=1: A pre-tiled [mB][kB][kq][r(128)][8] contiguous.
// ATILED=2 (R17): A tiled-packed into qkv V-columns -- chunk (mB,kB,kq) at
//   virtual row vr=mB*128+kB*4+kq, 1024 u16 contiguous (one row's V span);
//   staging = one 1KB-contiguous cp16/wave (was 16x64B strided in ATILED=0).
//   LDS layout identical to ATILED=1 -> fragment reads unchanged. MB must
//   be 64 (APW==1).
// ATILED=0: A row-major (lda).
// ---------------------------------------------------------------------------
template <int MB, int NT, int KK, int ATILED, int BK>
__global__ __launch_bounds__(256, 6) void gemm_bt(
    const u16* __restrict__ A, int lda, const u16* __restrict__ Bt,
    const void* __restrict__ bias, const int* __restrict__ fI32,
    void* __restrict__ C, int ropeMode, int outF,
    const void* __restrict__ cost, const void* __restrict__ sint, int N) {
  constexpr int MT = MB / 32;    // m fragments per wave
  constexpr int NTW = NT / 32;   // n fragments per wave
  constexpr int KSUB = BK / 32;  // 32-k chunks per step
  constexpr int KT = KK / BK;    // K steps
  constexpr int APW = MB / 64;   // A cp16 per wave per 32-k chunk
  constexpr int BPW = NT / 64;   // B cp16 per wave per 32-k chunk
  __shared__ __attribute__((aligned(16))) u16 As[KSUB * MB * 32];
  __shared__ __attribute__((aligned(16))) u16 Bs[KSUB * NT * 32];
  const int inf32 = *fI32;
  const int tid = threadIdx.x;
  const int wave = tid >> 6, lane = tid & 63, quad = lane >> 4, l16 = lane & 15;
  const int bx = blockIdx.x, by = blockIdx.y;
  const int m0 = by * MB, n0 = bx * NT;
  const int wm = (wave & 1) * (MB / 2), wn = (wave >> 1) * (NT / 2);
  f32x4 acc[MT][NTW];
#pragma unroll
  for (int i = 0; i < MT; i++)
#pragma unroll
    for (int j = 0; j < NTW; j++) acc[i][j] = (f32x4){0.f, 0.f, 0.f, 0.f};

  // staging source pointers (per-lane); LDS dests are wave-uniform.
  const u16* aT = nullptr;
  const u16* aP = nullptr;
  int mBv = 0, halfA = 0;
  if constexpr (ATILED == 1) {
    mBv = (MB == 128) ? by : (by >> 1);
    halfA = (MB == 128) ? 0 : (by & 1);
    aT = A + (size_t)mBv * KK * 128 + lane * 8;
  } else if constexpr (ATILED == 2) {
    mBv = by >> 1;
    halfA = by & 1;
    aT = A + lane * 8;  // A = base of packed V-column region (qkv+2048)
  } else {
    const int lr = lane >> 2, lk = (lane & 3) * 8;
    aP = A + (size_t)(m0 + wave * (MB / 4) + lr) * lda + lk;
  }
  const u16* bT = Bt + (size_t)bx * KK * NT + lane * 8;

  for (int s = 0; s < KT; ++s) {
    __syncthreads();
#pragma unroll
    for (int ks = 0; ks < KSUB; ks++) {
      const int kb32 = s * KSUB + ks;  // global 32-k block index
      if constexpr (ATILED == 1) {
#pragma unroll
        for (int j = 0; j < APW; j++) {
          const int c = wave * APW + j;
          size_t off;
          if constexpr (MB == 128) off = (size_t)kb32 * 4096 + c * 512;
          else                     off = (size_t)kb32 * 4096 + c * 1024 + halfA * 512;
          cp16(aT + off, As + ks * (MB * 32) + c * 512);
        }
      } else if constexpr (ATILED == 2) {
        // chunk (mBv, kb32, kq=wave) lives at virtual row vr, 1KB contiguous
        const int vr = mBv * 128 + kb32 * 4 + wave;
        cp16(aT + (size_t)vr * 3072 + halfA * 512,
             As + ks * (MB * 32) + wave * 512);
      } else {
#pragma unroll
        for (int j = 0; j < APW; j++)
          cp16(aP + kb32 * 32 + (size_t)(16 * j) * lda,
               As + ks * (MB * 32) + wave * (APW * 512) + j * 512);
      }
#pragma unroll
      for (int j = 0; j < BPW; j++) {
        const int c = wave * BPW + j;
        cp16(bT + (size_t)kb32 * (NT * 32) + c * 512,
             Bs + ks * (NT * 32) + c * 512);
      }
    }
    __syncthreads();
#pragma unroll
    for (int ks = 0; ks < KSUB; ks++) {
      s16x8 af[MT], bfr[NTW];
#pragma unroll
      for (int mt = 0; mt < MT; mt++) {
        if constexpr (ATILED != 0)
          af[mt] = *(const s16x8*)(As + ks * (MB * 32) + quad * (MB * 8) +
                                   (wm + mt * 16 + l16) * 8);
        else
          af[mt] = *(const s16x8*)(As + ks * (MB * 32) +
                                   (wm + mt * 16 + l16) * 32 + quad * 8);
      }
#pragma unroll
      for (int nt = 0; nt < NTW; nt++)
        bfr[nt] = *(const s16x8*)(Bs + ks * (NT * 32) + quad * (NT * 8) +
                                  (wn + nt * 16 + l16) * 8);
#pragma unroll
      for (int mt = 0; mt < MT; mt++)
#pragma unroll
        for (int nt = 0; nt < NTW; nt++)
          acc[mt][nt] = __builtin_amdgcn_mfma_f32_16x16x32_bf16(
              af[mt], bfr[nt], acc[mt][nt], 0, 0, 0);
    }
  }

#pragma unroll
  for (int nt = 0; nt < NTW; nt++) {
    int col = n0 + wn + nt * 16 + l16;
    float bv = loadf(bias, col, inf32);
    if (ropeMode && col < 2048) {
      int j = (col & 63) >> 1, odd = col & 1;
#pragma unroll
      for (int mt = 0; mt < MT; mt++)
#pragma unroll
        for (int r = 0; r < 4; r++) {
          int row = m0 + wm + mt * 16 + quad * 4 + r, t = row & 2047;
          float cv = loadf(cost, (size_t)t * 32 + j, inf32);
          float sv = loadf(sint, (size_t)t * 32 + j, inf32);
          float val = acc[mt][nt][r] + bv;
          float pr = __shfl_xor(val, 1);
          float res = odd ? (pr * sv + val * cv) : (val * cv - pr * sv);
          ((u16*)C)[(size_t)row * N + col] = f2bf(res);
        }
    } else if (outF && inf32) {  // final output, fp32
#pragma unroll
      for (int mt = 0; mt < MT; mt++)
#pragma unroll
        for (int r = 0; r < 4; r++) {
          int row = m0 + wm + mt * 16 + quad * 4 + r;
          ((float*)C)[(size_t)row * N + col] = acc[mt][nt][r] + bv;
        }
    } else {
#pragma unroll
      for (int mt = 0; mt < MT; mt++)
#pragma unroll
        for (int r = 0; r < 4; r++) {
          int row = m0 + wm + mt * 16 + quad * 4 + r;
          ((u16*)C)[(size_t)row * N + col] = f2bf(acc[mt][nt][r] + bv);
        }
    }
  }
}

// ---------------------------------------------------------------------------
// Causal flash attention v5 (R14-proven core, 43.8us, conflicts 0).
// R17 delta: y is written TILED-PACKED into the dead V-columns --
// element (grow,col) -> qkv[vr*3072 + 2048 + (grow&127)*8 + (col&7)] with
// vr = (grow>>7)*128 + (col>>5)*4 + ((col>>3)&3)  (bijective; same space,
// permuted). Feeds proj's ATILED=2 contiguous staging. Values bit-identical.
// ---------------------------------------------------------------------------
__device__ __forceinline__ int kvIdx(int chunk, int row) {  // 64-row tile
  return chunk * 512 + (((row & 56) | ((row ^ chunk) & 7)) << 3);
}
__device__ __forceinline__ int pIdx(int chunk, int row) {   // 16-row tile
  return chunk * 128 + (((row & 8) | ((row ^ chunk) & 7)) << 3);
}

__global__ __launch_bounds__(512) void attn_kernel(u16* qkv,
                                                   const u16* __restrict__ vT) {
  __shared__ __attribute__((aligned(16))) u16 Ks[8 * 512];
  __shared__ __attribute__((aligned(16))) u16 Vt[8 * 512];
  __shared__ __attribute__((aligned(16))) u16 Pl[8][8 * 128];
  const int tid = threadIdx.x;
  const int wave = tid >> 6, lane = tid & 63, quad = lane >> 4, l16 = lane & 15;
  const int cu = blockIdx.x & 255, round = blockIdx.x >> 8;
  const int p = cu >> 5, bh = cu & 31;
  const int qt = round ? p : 15 - p;  // heavy first
  const int h = bh & 15;
  const size_t rb = (size_t)(bh >> 4) * 2048;
  const int qb = qt * 128;
  const float SCALE = 0.18033688011112042f;  // 0.125 * log2(e)

  // Q fragment for this wave's 16 rows (direct from global, once)
  s16x8 qa0, qa1;
  {
    const u16* qp = qkv + (rb + qb + wave * 16 + l16) * 3072 + h * 64;
    qa0 = *(const s16x8*)(qp + quad * 8);
    qa1 = *(const s16x8*)(qp + 32 + quad * 8);
  }

  f32x4 o[4];
  float l_r[4] = {0.f, 0.f, 0.f, 0.f};
#pragma unroll
  for (int i = 0; i < 4; i++) o[i] = (f32x4){0.f, 0.f, 0.f, 0.f};

  const int nchunks = 2 * qt + 2;
  const int srow = tid >> 3, sc8 = tid & 7;  // 64 rows x 8 d-chunks staging
  const int stIdx = kvIdx(sc8, srow);        // swizzled staging granule
  s16x8 kr, vr;
  {
    kr = *(const s16x8*)(qkv + (rb + srow) * 3072 + 1024 + h * 64 + sc8 * 8);
    vr = *(const s16x8*)(vT + ((size_t)bh * 64 + srow) * 2048 + sc8 * 8);
  }

  for (int c = 0; c < nchunks; c++) {
    const int sb = c * 64;
    __syncthreads();  // previous compute done reading Ks/Vt
    *(s16x8*)(Ks + stIdx) = kr;
    *(s16x8*)(Vt + stIdx) = vr;
    __syncthreads();
    if (c + 1 < nchunks) {  // next chunk's global loads overlap compute
      const int nb = sb + 64;
      kr = *(const s16x8*)(qkv + (rb + nb + srow) * 3072 + 1024 + h * 64 +
                           sc8 * 8);
      vr = *(const s16x8*)(vT + ((size_t)bh * 64 + srow) * 2048 + nb + sc8 * 8);
    }

    // waves whose query range is entirely below this key chunk contribute 0
    if (sb > qb + wave * 16 + 15) continue;

    f32x4 S[4];
#pragma unroll
    for (int kf = 0; kf < 4; kf++) {
      s16x8 k0 = *(const s16x8*)(Ks + kvIdx(quad, kf * 16 + l16));
      s16x8 k1 = *(const s16x8*)(Ks + kvIdx(quad + 4, kf * 16 + l16));
      f32x4 a = (f32x4){0.f, 0.f, 0.f, 0.f};
      a = __builtin_amdgcn_mfma_f32_16x16x32_bf16(qa0, k0, a, 0, 0, 0);
      a = __builtin_amdgcn_mfma_f32_16x16x32_bf16(qa1, k1, a, 0, 0, 0);
      S[kf] = a;
    }

    // exp, mask-select, per-lane l accumulation, P write, single wait
    u16* P = Pl[wave];
    const int mq = qb + wave * 16;
    const bool needMask = (sb + 63) > mq;  // wave-uniform
#pragma unroll
    for (int r = 0; r < 4; r++) {
      const int qi = mq + quad * 4 + r;
#pragma unroll
      for (int kf = 0; kf < 4; kf++) {
        float pv = __builtin_amdgcn_exp2f(S[kf][r] * SCALE);
        if (needMask) pv = ((sb + kf * 16 + l16) <= qi) ? pv : 0.f;
        l_r[r] += pv;
        P[pIdx(kf * 2 + (l16 >> 3), quad * 4 + r) + (l16 & 7)] = f2bf_fast(pv);
      }
    }
    asm volatile("s_waitcnt lgkmcnt(0)" ::: "memory");
    s16x8 pa0 = *(const s16x8*)(P + pIdx(quad, l16));
    s16x8 pa1 = *(const s16x8*)(P + pIdx(quad + 4, l16));

#pragma unroll
    for (int dt = 0; dt < 4; dt++) {
      s16x8 vb0 = *(const s16x8*)(Vt + kvIdx(quad, dt * 16 + l16));
      s16x8 vb1 = *(const s16x8*)(Vt + kvIdx(quad + 4, dt * 16 + l16));
      o[dt] = __builtin_amdgcn_mfma_f32_16x16x32_bf16(pa0, vb0, o[dt], 0, 0, 0);
      o[dt] = __builtin_amdgcn_mfma_f32_16x16x32_bf16(pa1, vb1, o[dt], 0, 0, 0);
    }
  }

  // deferred cross-lane l reduction + y write (tiled-packed, see header)
  float inv[4];
#pragma unroll
  for (int r = 0; r < 4; r++) {
    float rs = l_r[r];
#pragma unroll
    for (int off = 8; off; off >>= 1) rs += __shfl_xor(rs, off);
    inv[r] = 1.0f / fmaxf(rs, 1e-30f);
  }
#pragma unroll
  for (int dt = 0; dt < 4; dt++)
#pragma unroll
    for (int r = 0; r < 4; r++) {
      const int grow = (int)rb + qb + wave * 16 + quad * 4 + r;
      const int col = h * 64 + dt * 16 + l16;
      const int vrow = (grow >> 7) * 128 + (col >> 5) * 4 + ((col >> 3) & 3);
      qkv[(size_t)vrow * 3072 + 2048 + (grow & 127) * 8 + (col & 7)] =
          f2bf(o[dt][r] * inv[r]);
    }
}

extern "C" void kernel_launch(void* const* d_in, const int* in_sizes, int n_in,
                              void* d_out, int out_size, void* d_ws,
                              size_t ws_size, hipStream_t stream) {
  const void* x = d_in[0];
  const void* Wqkv = d_in[1];
  const void* bqkv = d_in[2];
  const void* Wproj = d_in[3];
  const void* bproj = d_in[4];
  const void* cost = d_in[5];
  const void* sint = d_in[6];

  int* flags = (int*)d_ws;
  u16* WqkvT = (u16*)d_ws + 128;               // tiled [24][32][4][128][8]
  u16* WprojT = WqkvT + (size_t)3072 * 1024;   // tiled [16][32][4][64][8]
  u16* qkv = WprojT + (size_t)1024 * 1024;     // [4096][3072] bf16 row-major
  u16* yb = qkv + 2048;                        // y tiled-packed in the dead
                                               //   V-columns (R17 layout)
  u16* xb = (u16*)d_out;                       // tiled [32][32][4][128][8]
  u16* vT = (u16*)d_out + (size_t)4096 * 1024; // V^T (upper half; dead before
                                               //   final fp32 write)

  detect_dtype<<<1, 64, 0, stream>>>((const u16*)x, flags);
  convert_x<<<2048, 256, 0, stream>>>(x, flags, xb);
  transposeW2<<<dim3(64, 16), 256, 0, stream>>>(Wqkv, Wproj, flags, WqkvT,
                                                WprojT);
  gemm_bt<64, 128, 1024, 1, 64><<<dim3(24, 64), 256, 0, stream>>>(
      xb, 1024, WqkvT, bqkv, flags, qkv, 1, 0, cost, sint, 3072);
  transposeV<<<dim3(32, 32), 256, 0, stream>>>(qkv, vT);
  attn_kernel<<<512, 512, 0, stream>>>(qkv, vT);
  gemm_bt<64, 64, 1024, 2, 64><<<dim3(16, 64), 256, 0, stream>>>(
      yb, 3072, WprojT, bproj, flags, d_out, 0, 1, nullptr, nullptr, 1024);
}